// Round 4
// baseline (251.165 us; speedup 1.0000x reference)
//
#include <hip/hip_runtime.h>
#include <hip/hip_cooperative_groups.h>

namespace cg = cooperative_groups;

// T=8192 rows, H=4096 cols, f32 inputs.
// Outputs concat: [ q_dyn (T*H, f32-widened fp8), residual_out (T*H, f32) ]
//
// Cooperative single-kernel plan (512 MB HBM traffic):
//   1024 blocks x 256 threads, 8 rows/block. Pass1: add+RMSNorm+static quant,
//   fp8 words parked in LDS (32KB/block), per-block max -> ws. grid.sync().
//   Global amax reduce (4KB, L2). Pass2: requant from LDS -> q_dyn.

typedef float v2f __attribute__((ext_vector_type(2)));
typedef float v4f __attribute__((ext_vector_type(4)));   // native vec for nontemporal builtins

static constexpr int H_DIM = 4096;
#define FP8_MAX_F 448.0f

__device__ __forceinline__ unsigned int quant4(float q0, float q1, float q2, float q3) {
    unsigned int pk = 0;
    pk = __builtin_amdgcn_cvt_pk_fp8_f32(q0, q1, pk, false); // bytes 0,1
    pk = __builtin_amdgcn_cvt_pk_fp8_f32(q2, q3, pk, true);  // bytes 2,3
    return pk;
}

__device__ __forceinline__ float fp8_roundtrip1(float x) {
    unsigned int pk = __builtin_amdgcn_cvt_pk_fp8_f32(x, x, 0, false);
    v2f d = __builtin_amdgcn_cvt_pk_f32_fp8((int)pk, false);
    return d[0];
}

// ---------------- Cooperative fused kernel ----------------
__global__ __launch_bounds__(256, 4) void k_fused(
    const float* __restrict__ hs, const float* __restrict__ res,
    const float* __restrict__ w, const float* __restrict__ scale_p,
    float* __restrict__ q_dyn, float* __restrict__ resid_out,
    float* __restrict__ blockmax)
{
    __shared__ unsigned int q8[8][1024];   // 32 KB: fp8 words for 8 rows
    __shared__ double sred[4];
    __shared__ float smax[4];

    const int t = threadIdx.x, lane = t & 63, wid = t >> 6;
    const int bid = blockIdx.x;
    const float s = scale_p[0];

    // Cache this thread's 16 weight values (same columns for every row).
    v4f wv[4];
#pragma unroll
    for (int c = 0; c < 4; ++c)
        wv[c] = *(const v4f*)(w + c * 1024 + t * 4);

    float lmax = 0.0f;

#pragma unroll 1
    for (int r = 0; r < 8; ++r) {
        const size_t base = ((size_t)bid * 8 + r) * H_DIM;

        v4f a[4];
        double ss = 0.0;
#pragma unroll
        for (int c = 0; c < 4; ++c) {
            const int col = c * 1024 + t * 4;
            const v4f hv = __builtin_nontemporal_load((const v4f*)(hs + base + col));
            const v4f rv = __builtin_nontemporal_load((const v4f*)(res + base + col));
            const v4f av = hv + rv;
            a[c] = av;
            __builtin_nontemporal_store(av, (v4f*)(resid_out + base + col));
            ss += (double)av.x * (double)av.x + (double)av.y * (double)av.y
                + (double)av.z * (double)av.z + (double)av.w * (double)av.w;
        }

        // Block reduction of sum-of-squares (4 waves of 64).
#pragma unroll
        for (int o = 32; o > 0; o >>= 1) ss += __shfl_down(ss, o, 64);
        if (lane == 0) sred[wid] = ss;
        __syncthreads();
        const double tot = sred[0] + sred[1] + sred[2] + sred[3];
        __syncthreads();   // sred reused next row
        const float inv = (float)(1.0 / sqrt(tot / (double)H_DIM + 1e-6));

#pragma unroll
        for (int c = 0; c < 4; ++c) {
            const v4f av = a[c];
            float q0 = (av.x * inv) * wv[c].x / s;
            float q1 = (av.y * inv) * wv[c].y / s;
            float q2 = (av.z * inv) * wv[c].z / s;
            float q3 = (av.w * inv) * wv[c].w / s;
            q0 = fminf(fmaxf(q0, -FP8_MAX_F), FP8_MAX_F);
            q1 = fminf(fmaxf(q1, -FP8_MAX_F), FP8_MAX_F);
            q2 = fminf(fmaxf(q2, -FP8_MAX_F), FP8_MAX_F);
            q3 = fminf(fmaxf(q3, -FP8_MAX_F), FP8_MAX_F);
            q8[r][c * 256 + t] = quant4(q0, q1, q2, q3);
            // max|deq| == roundtrip(max|q|): RNE quant monotone & symmetric.
            lmax = fmaxf(lmax, fmaxf(fmaxf(fabsf(q0), fabsf(q1)),
                                     fmaxf(fabsf(q2), fabsf(q3))));
        }
    }

    // Per-block max -> ws (plain store; array fully rewritten every call).
#pragma unroll
    for (int o = 32; o > 0; o >>= 1) lmax = fmaxf(lmax, __shfl_down(lmax, o, 64));
    if (lane == 0) smax[wid] = lmax;
    __syncthreads();
    if (t == 0)
        blockmax[bid] = fmaxf(fmaxf(smax[0], smax[1]), fmaxf(smax[2], smax[3]));

    cg::this_grid().sync();

    // Global amax: every block reduces the 1024-entry array (L2-resident).
    float m = 0.0f;
    {
        const v4f v = *(const v4f*)(blockmax + t * 4);   // 256*4 == 1024
        m = fmaxf(fmaxf(v.x, v.y), fmaxf(v.z, v.w));
#pragma unroll
        for (int o = 32; o > 0; o >>= 1) m = fmaxf(m, __shfl_down(m, o, 64));
        if (lane == 0) smax[wid] = m;
        __syncthreads();
    }
    const float amax   = fp8_roundtrip1(fmaxf(fmaxf(smax[0], smax[1]),
                                              fmaxf(smax[2], smax[3])));
    const float dscale = fmaxf(amax, 1e-12f) / FP8_MAX_F;

    // Pass 2: dynamic requant from LDS fp8 words.
#pragma unroll 1
    for (int r = 0; r < 8; ++r) {
        const size_t base = ((size_t)bid * 8 + r) * H_DIM;
#pragma unroll
        for (int c = 0; c < 4; ++c) {
            const unsigned int pw = q8[r][c * 256 + t];
            const v2f lo = __builtin_amdgcn_cvt_pk_f32_fp8((int)pw, false);
            const v2f hi = __builtin_amdgcn_cvt_pk_f32_fp8((int)pw, true);
            float q0 = lo[0] / dscale, q1 = lo[1] / dscale;
            float q2 = hi[0] / dscale, q3 = hi[1] / dscale;
            q0 = fminf(fmaxf(q0, -FP8_MAX_F), FP8_MAX_F);
            q1 = fminf(fmaxf(q1, -FP8_MAX_F), FP8_MAX_F);
            q2 = fminf(fmaxf(q2, -FP8_MAX_F), FP8_MAX_F);
            q3 = fminf(fmaxf(q3, -FP8_MAX_F), FP8_MAX_F);
            const unsigned int rq = quant4(q0, q1, q2, q3);
            const v2f olo = __builtin_amdgcn_cvt_pk_f32_fp8((int)rq, false);
            const v2f ohi = __builtin_amdgcn_cvt_pk_f32_fp8((int)rq, true);
            v4f ov; ov.x = olo[0]; ov.y = olo[1]; ov.z = ohi[0]; ov.w = ohi[1];
            __builtin_nontemporal_store(ov, (v4f*)(q_dyn + base + c * 1024 + t * 4));
        }
    }
}

// ---------------- Fallback: R2's two-kernel path ----------------
__global__ __launch_bounds__(256) void k_rms_quant(
    const float* __restrict__ hs, const float* __restrict__ res,
    const float* __restrict__ w, const float* __restrict__ scale_p,
    float* __restrict__ resid_out, unsigned int* __restrict__ q8w,
    float* __restrict__ blockmax)
{
    const int row = blockIdx.x;
    const int t   = threadIdx.x;
    const size_t base  = (size_t)row * H_DIM;
    const size_t base4 = base >> 2;

    float4 a[4];
    double ss = 0.0;
#pragma unroll
    for (int c = 0; c < 4; ++c) {
        const int col = c * 1024 + t * 4;
        const float4 hv = *(const float4*)(hs + base + col);
        const float4 rv = *(const float4*)(res + base + col);
        float4 av;
        av.x = hv.x + rv.x; av.y = hv.y + rv.y;
        av.z = hv.z + rv.z; av.w = hv.w + rv.w;
        a[c] = av;
        *(float4*)(resid_out + base + col) = av;
        ss += (double)av.x * (double)av.x + (double)av.y * (double)av.y
            + (double)av.z * (double)av.z + (double)av.w * (double)av.w;
    }
    __shared__ double sred[4];
#pragma unroll
    for (int o = 32; o > 0; o >>= 1) ss += __shfl_down(ss, o, 64);
    const int lane = t & 63, wid = t >> 6;
    if (lane == 0) sred[wid] = ss;
    __syncthreads();
    if (t == 0) sred[0] = sred[0] + sred[1] + sred[2] + sred[3];
    __syncthreads();
    const float inv = (float)(1.0 / sqrt(sred[0] / (double)H_DIM + 1e-6));

    const float s = scale_p[0];
    float lmax = 0.0f;
#pragma unroll
    for (int c = 0; c < 4; ++c) {
        const int col = c * 1024 + t * 4;
        const float4 wv = *(const float4*)(w + col);
        const float4 av = a[c];
        float q0 = (av.x * inv) * wv.x / s;
        float q1 = (av.y * inv) * wv.y / s;
        float q2 = (av.z * inv) * wv.z / s;
        float q3 = (av.w * inv) * wv.w / s;
        q0 = fminf(fmaxf(q0, -FP8_MAX_F), FP8_MAX_F);
        q1 = fminf(fmaxf(q1, -FP8_MAX_F), FP8_MAX_F);
        q2 = fminf(fmaxf(q2, -FP8_MAX_F), FP8_MAX_F);
        q3 = fminf(fmaxf(q3, -FP8_MAX_F), FP8_MAX_F);
        q8w[base4 + c * 256 + t] = quant4(q0, q1, q2, q3);
        lmax = fmaxf(lmax, fmaxf(fmaxf(fabsf(q0), fabsf(q1)),
                                 fmaxf(fabsf(q2), fabsf(q3))));
    }
    __shared__ float smax[4];
#pragma unroll
    for (int o = 32; o > 0; o >>= 1) lmax = fmaxf(lmax, __shfl_down(lmax, o, 64));
    if (lane == 0) smax[wid] = lmax;
    __syncthreads();
    if (t == 0)
        blockmax[row] = fmaxf(fmaxf(smax[0], smax[1]), fmaxf(smax[2], smax[3]));
}

__global__ __launch_bounds__(256) void k_requant(
    const unsigned int* __restrict__ q8w,
    const float* __restrict__ blockmax, int nblk,
    float* __restrict__ out, size_t nwords)
{
    const int t = threadIdx.x;
    const int lane = t & 63, wid = t >> 6;
    float m = 0.0f;
    for (int i = t * 4; i < nblk; i += 256 * 4) {
        const float4 v = *(const float4*)(blockmax + i);
        m = fmaxf(fmaxf(m, fmaxf(v.x, v.y)), fmaxf(v.z, v.w));
    }
#pragma unroll
    for (int o = 32; o > 0; o >>= 1) m = fmaxf(m, __shfl_down(m, o, 64));
    __shared__ float sm[4];
    if (lane == 0) sm[wid] = m;
    __syncthreads();
    const float amax   = fp8_roundtrip1(fmaxf(fmaxf(sm[0], sm[1]), fmaxf(sm[2], sm[3])));
    const float dscale = fmaxf(amax, 1e-12f) / FP8_MAX_F;

    size_t i = ((size_t)blockIdx.x * 256 + t) * 2;
    const size_t stride = (size_t)gridDim.x * 256 * 2;
    for (; i + 1 < nwords; i += stride) {
        const uint2 pw = *(const uint2*)(q8w + i);
#pragma unroll
        for (int j = 0; j < 2; ++j) {
            const unsigned int wv = j ? pw.y : pw.x;
            const v2f lo = __builtin_amdgcn_cvt_pk_f32_fp8((int)wv, false);
            const v2f hi = __builtin_amdgcn_cvt_pk_f32_fp8((int)wv, true);
            float q0 = lo[0] / dscale, q1 = lo[1] / dscale;
            float q2 = hi[0] / dscale, q3 = hi[1] / dscale;
            q0 = fminf(fmaxf(q0, -FP8_MAX_F), FP8_MAX_F);
            q1 = fminf(fmaxf(q1, -FP8_MAX_F), FP8_MAX_F);
            q2 = fminf(fmaxf(q2, -FP8_MAX_F), FP8_MAX_F);
            q3 = fminf(fmaxf(q3, -FP8_MAX_F), FP8_MAX_F);
            const unsigned int rq = quant4(q0, q1, q2, q3);
            const v2f olo = __builtin_amdgcn_cvt_pk_f32_fp8((int)rq, false);
            const v2f ohi = __builtin_amdgcn_cvt_pk_f32_fp8((int)rq, true);
            *(float4*)(out + (i + j) * 4) = make_float4(olo[0], olo[1], ohi[0], ohi[1]);
        }
    }
}

extern "C" void kernel_launch(void* const* d_in, const int* in_sizes, int n_in,
                              void* d_out, int out_size, void* d_ws, size_t ws_size,
                              hipStream_t stream) {
    const float* hs    = (const float*)d_in[0];
    const float* res   = (const float*)d_in[1];
    const float* w     = (const float*)d_in[2];
    const float* scale = (const float*)d_in[3];
    const int Hn = in_sizes[2];           // 4096
    const int Tn = in_sizes[0] / Hn;      // 8192
    const size_t nelem  = (size_t)Tn * Hn;
    const size_t nwords = nelem / 4;

    float* q_dyn_out = (float*)d_out;
    float* resid_out = (float*)d_out + nelem;

    float* blockmax = (float*)d_ws;
    unsigned int* q8w = (unsigned int*)((float*)d_ws + 2 * Tn);

    bool done = false;
    if (Hn == H_DIM && Tn == 8192 && ws_size >= 4096 * 4) {
        void* args[] = { (void*)&hs, (void*)&res, (void*)&w, (void*)&scale,
                         (void*)&q_dyn_out, (void*)&resid_out, (void*)&blockmax };
        hipError_t e = hipLaunchCooperativeKernel((const void*)k_fused,
                                                  dim3(1024), dim3(256),
                                                  args, 0, stream);
        done = (e == hipSuccess);
    }

    if (!done && ws_size >= (size_t)2 * Tn * 4 + nelem) {
        k_rms_quant<<<Tn, 256, 0, stream>>>(hs, res, w, scale,
                                            resid_out, q8w, blockmax);
        k_requant<<<2048, 256, 0, stream>>>(q8w, blockmax, Tn, q_dyn_out, nwords);
    }
}